// Round 6
// baseline (208.322 us; speedup 1.0000x reference)
//
#include <hip/hip_runtime.h>
#include <stdint.h>

#define BATCH 32
#define CIN   64
#define HH    112
#define WW    112
#define COUT_ 64

typedef int v4i __attribute__((ext_vector_type(4)));

// d_ws: only the transposed weights. 36,864 B.

// Weight transpose: [co][ci][kh][kw] -> [co][tap][ci] so A-fragments
// (16 consecutive k = contiguous ci at a fixed tap) are direct loads.
__global__ void wtrans_kernel(const int* __restrict__ wq, int8_t* __restrict__ wt) {
    int idx = blockIdx.x * 256 + threadIdx.x;   // 0 .. 36863, exact
    int ci   = idx & 63;
    int khkw = (idx >> 6) % 9;
    int co   = idx / 576;
    wt[idx] = (int8_t)wq[co * 576 + ci * 9 + khkw];
}

// Fused conv kernel v7: single pass, 896 blocks = 32 b x 28 h-groups of
// 4 output rows (2 tiles), XCD-chunked. LDS = 6 input rows (43,776 B ->
// 2 blocks/CU co-resident, 8 waves/CU). Rows hb-1..hb+4 -> phys 0..5,
// no ring wrap. Pipeline: prologue stages phys 0..3; iter 0 prefetches
// phys 4,5 (loads in flight under tile-0 MFMA, narrow+ds_write after,
// T14 split); tile 1 computes with no staging; stores overlap next phase.
__launch_bounds__(256, 2)
__global__ void conv5_kernel(const int* __restrict__ x,
                             const int8_t* __restrict__ wt,
                             const float*  __restrict__ wscale,
                             const float*  __restrict__ ascale,
                             const float*  __restrict__ bias,
                             float*        __restrict__ out) {
    __shared__ int8_t xs[6 * 114 * 64];   // 43,776 B

    const int tid = threadIdx.x;
    // XCD-chunked swizzle: 896 = 8 XCDs x 112 contiguous groups
    const int bt = ((blockIdx.x & 7) * 112) + (blockIdx.x >> 3);
    const int b  = bt / 28;
    const int hb = (bt % 28) * 4;         // this block's 4 output rows

    const int lane = tid & 63;
    const int wave = tid >> 6;            // co-tile 0..3
    const int ln15 = lane & 15;
    const int quad = lane >> 4;

    // one-time: zero W-pad columns 0 and 113 of all 6 rows (192 jobs)
    if (tid < 192) {
        int pr   = tid >> 5;
        int side = (tid >> 4) & 1;
        int d    = tid & 15;
        *(uint32_t*)&xs[pr * 7296 + (side ? 113 : 0) * 64 + d * 4] = 0u;
    }

    // preload A fragments: wt[co][tap*64 + quad*16 .. +15]
    const v4i* wrow = (const v4i*)(wt + (size_t)(wave * 16 + ln15) * 576);
    v4i a[9];
    #pragma unroll
    for (int t = 0; t < 9; ++t) a[t] = wrow[t * 4 + quad];

    const float s = ascale[0] * wscale[0];
    float bv[4];
    #pragma unroll
    for (int reg = 0; reg < 4; ++reg) bv[reg] = bias[wave * 16 + quad * 4 + reg];

    // ---- 2-row staging, split: load (to regs) / write (narrow -> LDS) ----
    // 896 jobs = 2 rows x 28 colgroups x 16 ci4; job: 4 int4 loads (4 ci
    // planes x 4 pixels); lanes cover cg -> coalesced 64B lines. OOB rows
    // stay zero (H padding).
    v4i q[16];
    auto stage_load = [&](int hstart) {
        #pragma unroll
        for (int it = 0; it < 4; ++it) {
            #pragma unroll
            for (int p = 0; p < 4; ++p) q[it * 4 + p] = (v4i){0, 0, 0, 0};
            int job = tid + it * 256;
            if (job < 896) {
                int ci4  = job & 15;
                int cg   = (job >> 4) % 28;
                int row2 = job / 448;
                int hh   = hstart + row2;
                if (hh >= 0 && hh < HH) {
                    const v4i* gp = (const v4i*)
                        (x + ((size_t)(b * CIN + ci4 * 4) * HH + hh) * WW + cg * 4);
                    q[it * 4 + 0] = gp[0];
                    q[it * 4 + 1] = gp[3136];      // +1 ci plane
                    q[it * 4 + 2] = gp[2 * 3136];
                    q[it * 4 + 3] = gp[3 * 3136];
                }
            }
        }
    };
    // narrow + swizzled LDS write; per-instr 16 lanes hit 16 distinct dwords
    // of one 64B pixel (bijective sd) -> conflict-free.
    auto stage_write = [&](int pb) {
        #pragma unroll
        for (int it = 0; it < 4; ++it) {
            int job = tid + it * 256;
            if (job < 896) {
                int ci4  = job & 15;
                int cg   = (job >> 4) % 28;
                int row2 = job / 448;
                int8_t* rowp = &xs[(pb + row2) * 7296];
                #pragma unroll
                for (int j = 0; j < 4; ++j) {
                    uint32_t lo01 = __builtin_amdgcn_perm(
                        (uint32_t)q[it * 4 + 1][j], (uint32_t)q[it * 4 + 0][j], 0x0C0C0400u);
                    uint32_t lo23 = __builtin_amdgcn_perm(
                        (uint32_t)q[it * 4 + 3][j], (uint32_t)q[it * 4 + 2][j], 0x04000C0Cu);
                    int col = cg * 4 + 1 + j;   // +1: W-pad shift
                    int sd  = (((ci4 >> 2) ^ ((col >> 1) & 3)) << 2) | (ci4 & 3);
                    *(uint32_t*)&rowp[col * 64 + sd * 4] = lo01 | lo23;
                }
            }
        }
    };

    v4i acc[2][7];
    // MFMA for one tile: reads phys rows rbase..rbase+3; each bfrag serves
    // acc[0] (kh=rho) and acc[1] (kh=rho-1): 84 ds_read_b128 : 126 MFMA.
    auto mfma_tile = [&](int rbase) {
        #pragma unroll
        for (int r = 0; r < 2; ++r)
            #pragma unroll
            for (int nt = 0; nt < 7; ++nt)
                acc[r][nt] = (v4i){0, 0, 0, 0};
        #pragma unroll
        for (int rho = 0; rho < 4; ++rho) {
            const int pr = rbase + rho;
            #pragma unroll
            for (int kw = 0; kw < 3; ++kw) {
                const int m   = ln15 + kw;                     // col in 16-col tile
                const int swz = (quad ^ ((m >> 1) & 3)) << 4;  // nt*16-invariant
                const int8_t* bp = &xs[pr * 7296 + m * 64 + swz];
                #pragma unroll
                for (int nt = 0; nt < 7; ++nt) {
                    v4i bfrag = *(const v4i*)(bp + nt * 1024);
                    if (rho <= 2)
                        acc[0][nt] = __builtin_amdgcn_mfma_i32_16x16x64_i8(
                            a[rho * 3 + kw], bfrag, acc[0][nt], 0, 0, 0);
                    if (rho >= 1)
                        acc[1][nt] = __builtin_amdgcn_mfma_i32_16x16x64_i8(
                            a[(rho - 1) * 3 + kw], bfrag, acc[1][nt], 0, 0, 0);
                }
            }
        }
    };
    auto store_tile = [&](int h0) {
        #pragma unroll
        for (int r = 0; r < 2; ++r) {
            const int h = h0 + r;
            #pragma unroll
            for (int reg = 0; reg < 4; ++reg) {
                int co = wave * 16 + quad * 4 + reg;
                float* op = out + ((size_t)(b * COUT_ + co) * HH + h) * WW;
                #pragma unroll
                for (int nt = 0; nt < 7; ++nt)
                    op[nt * 16 + ln15] = (float)acc[r][nt][reg] * s + bv[reg];
            }
        }
    };

    // ---- prologue: stage phys 0..3 (rows hb-1 .. hb+2) ----
    stage_load(hb - 1);
    asm volatile("s_waitcnt vmcnt(0)" ::: "memory");
    stage_write(0);
    stage_load(hb + 1);
    asm volatile("s_waitcnt vmcnt(0)" ::: "memory");
    stage_write(2);
    asm volatile("s_waitcnt lgkmcnt(0)" ::: "memory");
    __builtin_amdgcn_s_barrier();
    __builtin_amdgcn_sched_barrier(0);

    // ---- tile 0: prefetch rows hb+3,hb+4 under the MFMA ----
    stage_load(hb + 3);
    __builtin_amdgcn_sched_barrier(0);
    mfma_tile(0);
    __builtin_amdgcn_sched_barrier(0);
    asm volatile("s_waitcnt vmcnt(0)" ::: "memory");
    stage_write(4);
    asm volatile("s_waitcnt lgkmcnt(0)" ::: "memory");
    __builtin_amdgcn_s_barrier();
    __builtin_amdgcn_sched_barrier(0);
    store_tile(hb);          // overlaps tile 1's MFMA

    // ---- tile 1: no staging ----
    mfma_tile(2);
    store_tile(hb + 2);
}

extern "C" void kernel_launch(void* const* d_in, const int* in_sizes, int n_in,
                              void* d_out, int out_size, void* d_ws, size_t ws_size,
                              hipStream_t stream) {
    const int*    xq     = (const int*)d_in[0];
    const int*    wq     = (const int*)d_in[1];
    const float*  wscale = (const float*)d_in[2];
    const float*  ascale = (const float*)d_in[3];
    const float*  bias   = (const float*)d_in[4];
    int8_t* wt  = (int8_t*)d_ws;          // 36,864 B scratch
    float*  out = (float*)d_out;

    wtrans_kernel<<<144, 256, 0, stream>>>(wq, wt);
    conv5_kernel<<<896, 256, 0, stream>>>(xq, wt, wscale, ascale, bias, out);
}

// Round 7
// 195.923 us; speedup vs baseline: 1.0633x; 1.0633x over previous
//
#include <hip/hip_runtime.h>
#include <stdint.h>

#define BATCH 32
#define CIN   64
#define HH    112
#define WW    112
#define COUT_ 64

typedef int v4i __attribute__((ext_vector_type(4)));

// Weight transpose: [co][ci][kh][kw] -> [co][tap][ci] so A-fragments
// (16 consecutive k = contiguous ci at a fixed tap) are direct loads.
__global__ void wtrans_kernel(const int* __restrict__ wq, int8_t* __restrict__ wt) {
    int idx = blockIdx.x * 256 + threadIdx.x;   // 0 .. 36863, exact
    int ci   = idx & 63;
    int khkw = (idx >> 6) % 9;
    int co   = idx / 576;
    wt[idx] = (int8_t)wq[co * 576 + ci * 9 + khkw];
}

// Fused conv v8: producer-consumer wave specialization.
// 256 blocks (1/CU) x 512 threads = 2 groups of 4 waves. 8-row LDS ring.
// Phase s (one barrier each): group (s&1) computes tile s (MFMA only);
// the other group drains its 2-phase-old loads, ds_writes rows 2s+4/5,
// issues loads for rows 2s+8/9, and stores tile s-1. Ring safety:
// writes {2s+4,2s+5}&7 disjoint from reads {2s..2s+3}&7; written rows
// last read by tile s-2 (two barriers ago). Loader == writer (q regs
// stay in-group, live across one compute phase; ~180 VGPR, 2 waves/SIMD).
__launch_bounds__(512, 2)
__global__ void conv6_kernel(const int* __restrict__ x,
                             const int8_t* __restrict__ wt,
                             const float*  __restrict__ wscale,
                             const float*  __restrict__ ascale,
                             const float*  __restrict__ bias,
                             float*        __restrict__ out) {
    __shared__ int8_t xs[8 * 114 * 64];   // 58,368 B ring

    const int tid  = threadIdx.x;          // 0..511
    const int g    = tid >> 8;             // wave-group 0/1
    const int stid = tid & 255;            // id within group
    const int b    = blockIdx.x >> 3;
    const int hb   = (blockIdx.x & 7) * 14;

    const int lane = tid & 63;
    const int wave = (tid >> 6) & 3;       // co-tile within group
    const int ln15 = lane & 15;
    const int quad = lane >> 4;

    // one-time: zero W-pad columns 0 and 113 of all 8 ring rows (256 jobs)
    if (tid < 256) {
        int pr   = tid >> 5;
        int side = (tid >> 4) & 1;
        int d    = tid & 15;
        *(uint32_t*)&xs[pr * 7296 + (side ? 113 : 0) * 64 + d * 4] = 0u;
    }

    // A fragments: wt[co][tap*64 + quad*16 .. +15]
    const v4i* wrow = (const v4i*)(wt + (size_t)(wave * 16 + ln15) * 576);
    v4i a[9];
    #pragma unroll
    for (int t = 0; t < 9; ++t) a[t] = wrow[t * 4 + quad];

    const float s = ascale[0] * wscale[0];
    float bv[4];
    #pragma unroll
    for (int reg = 0; reg < 4; ++reg) bv[reg] = bias[wave * 16 + quad * 4 + reg];

    // ---- group-local 2-row staging: load to regs / narrow+swizzle to LDS ----
    // 896 jobs over 256 group-threads; 4 int4 loads per job (4 ci planes x
    // 4 pixels), fully coalesced 64B lines. OOB rows stay zero (H padding).
    v4i q[16];
    auto stage_load = [&](int hstart) {
        #pragma unroll
        for (int it = 0; it < 4; ++it) {
            #pragma unroll
            for (int p = 0; p < 4; ++p) q[it * 4 + p] = (v4i){0, 0, 0, 0};
            int job = stid + it * 256;
            if (job < 896) {
                int ci4  = job & 15;
                int cg   = (job >> 4) % 28;
                int row2 = job / 448;
                int hh   = hstart + row2;
                if (hh >= 0 && hh < HH) {
                    const v4i* gp = (const v4i*)
                        (x + ((size_t)(b * CIN + ci4 * 4) * HH + hh) * WW + cg * 4);
                    q[it * 4 + 0] = gp[0];
                    q[it * 4 + 1] = gp[3136];      // +1 ci plane
                    q[it * 4 + 2] = gp[2 * 3136];
                    q[it * 4 + 3] = gp[3 * 3136];
                }
            }
        }
    };
    // pb is an EVEN ring row (masked at base; pair never wraps).
    auto stage_write = [&](int pb) {
        #pragma unroll
        for (int it = 0; it < 4; ++it) {
            int job = stid + it * 256;
            if (job < 896) {
                int ci4  = job & 15;
                int cg   = (job >> 4) % 28;
                int row2 = job / 448;
                int8_t* rowp = &xs[((pb & 7) + row2) * 7296];
                #pragma unroll
                for (int j = 0; j < 4; ++j) {
                    uint32_t lo01 = __builtin_amdgcn_perm(
                        (uint32_t)q[it * 4 + 1][j], (uint32_t)q[it * 4 + 0][j], 0x0C0C0400u);
                    uint32_t lo23 = __builtin_amdgcn_perm(
                        (uint32_t)q[it * 4 + 3][j], (uint32_t)q[it * 4 + 2][j], 0x04000C0Cu);
                    int col = cg * 4 + 1 + j;   // +1: W-pad shift
                    int sd  = (((ci4 >> 2) ^ ((col >> 1) & 3)) << 2) | (ci4 & 3);
                    *(uint32_t*)&rowp[col * 64 + sd * 4] = lo01 | lo23;
                }
            }
        }
    };

    v4i acc[2][7];
    // tile at ring rows (rbase+rho)&7; each bfrag feeds acc[0] (kh=rho) and
    // acc[1] (kh=rho-1): 84 ds_read_b128 : 126 MFMA per wave, conflict-free.
    auto mfma_tile = [&](int rbase) {
        #pragma unroll
        for (int r = 0; r < 2; ++r)
            #pragma unroll
            for (int nt = 0; nt < 7; ++nt)
                acc[r][nt] = (v4i){0, 0, 0, 0};
        #pragma unroll
        for (int rho = 0; rho < 4; ++rho) {
            const int pr = (rbase + rho) & 7;
            #pragma unroll
            for (int kw = 0; kw < 3; ++kw) {
                const int m   = ln15 + kw;
                const int swz = (quad ^ ((m >> 1) & 3)) << 4;
                const int8_t* bp = &xs[pr * 7296 + m * 64 + swz];
                #pragma unroll
                for (int nt = 0; nt < 7; ++nt) {
                    v4i bfrag = *(const v4i*)(bp + nt * 1024);
                    if (rho <= 2)
                        acc[0][nt] = __builtin_amdgcn_mfma_i32_16x16x64_i8(
                            a[rho * 3 + kw], bfrag, acc[0][nt], 0, 0, 0);
                    if (rho >= 1)
                        acc[1][nt] = __builtin_amdgcn_mfma_i32_16x16x64_i8(
                            a[(rho - 1) * 3 + kw], bfrag, acc[1][nt], 0, 0, 0);
                }
            }
        }
    };
    auto store_tile = [&](int t) {
        const int h0 = hb + 2 * t;
        #pragma unroll
        for (int r = 0; r < 2; ++r) {
            const int h = h0 + r;
            #pragma unroll
            for (int reg = 0; reg < 4; ++reg) {
                int co = wave * 16 + quad * 4 + reg;
                float* op = out + ((size_t)(b * COUT_ + co) * HH + h) * WW;
                #pragma unroll
                for (int nt = 0; nt < 7; ++nt)
                    op[nt * 16 + ln15] = (float)acc[r][nt][reg] * s + bv[reg];
            }
        }
    };

    // ---- prologue ----
    // g0 stages ring rows 0,1 (hh hb-1,hb); g1 stages rows 2,3 (hh hb+1,hb+2)
    stage_load(hb - 1 + 2 * g);
    asm volatile("s_waitcnt vmcnt(0)" ::: "memory");
    stage_write(2 * g);
    // issue-ahead: g1 loads rows 4,5 (writes them at s=0); g0 rows 6,7 (s=1)
    stage_load(hb + 3 + ((g ^ 1) << 1));
    asm volatile("s_waitcnt lgkmcnt(0)" ::: "memory");
    __builtin_amdgcn_s_barrier();
    __builtin_amdgcn_sched_barrier(0);

    // ---- 7 phases, one barrier each ----
    #pragma unroll 1
    for (int ph = 0; ph < 7; ++ph) {
        if ((ph & 1) == g) {
            // compute group: tile ph from ring rows (2*ph .. 2*ph+3)&7
            __builtin_amdgcn_s_setprio(1);
            mfma_tile(2 * ph);
            __builtin_amdgcn_s_setprio(0);
        } else {
            // stager group: drain own 2-phase-old loads, write rows 2ph+4/5,
            // issue loads for rows 2ph+8/9, store tile ph-1 (own acc).
            asm volatile("s_waitcnt vmcnt(0)" ::: "memory");
            if (ph <= 5) stage_write(2 * ph + 4);
            if (ph <= 3) stage_load(hb + 2 * ph + 7);
            if (ph >= 1) store_tile(ph - 1);
        }
        __builtin_amdgcn_sched_barrier(0);
        if (ph < 6) {
            asm volatile("s_waitcnt lgkmcnt(0)" ::: "memory");
            __builtin_amdgcn_s_barrier();
            __builtin_amdgcn_sched_barrier(0);
        }
    }
    // tile 6 was computed by g0 in the last phase; store it directly.
    if (g == 0) store_tile(6);
}

extern "C" void kernel_launch(void* const* d_in, const int* in_sizes, int n_in,
                              void* d_out, int out_size, void* d_ws, size_t ws_size,
                              hipStream_t stream) {
    const int*    xq     = (const int*)d_in[0];
    const int*    wq     = (const int*)d_in[1];
    const float*  wscale = (const float*)d_in[2];
    const float*  ascale = (const float*)d_in[3];
    const float*  bias   = (const float*)d_in[4];
    int8_t* wt  = (int8_t*)d_ws;          // 36,864 B scratch
    float*  out = (float*)d_out;

    wtrans_kernel<<<144, 256, 0, stream>>>(wq, wt);
    conv6_kernel<<<256, 512, 0, stream>>>(xq, wt, wscale, ascale, bias, out);
}